// Round 11
// baseline (560.734 us; speedup 1.0000x reference)
//
#include <hip/hip_runtime.h>

// db2 filters, pre-flipped (cross-correlation form used by ptwt)
#define F_LO0 0.4829629131445341f
#define F_LO1 0.8365163037378079f
#define F_LO2 0.22414386804185735f
#define F_LO3 (-0.12940952255092145f)
#define F_HI0 (-0.12940952255092145f)
#define F_HI1 (-0.22414386804185735f)
#define F_HI2 0.8365163037378079f
#define F_HI3 (-0.4829629131445341f)

__device__ __forceinline__ int reflect_idx(int r, int n) {
    r = (r < 0) ? -r : r;
    r = (r >= n) ? 2 * n - 2 - r : r;
    return r;
}

// Fused 3-level WPT + weighted squared-sum.
// R11: LDS diet 52KB -> 38.2KB => 4 blocks/CU (32 waves/CU, HW cap) instead of 3.
//  (a) h1 fused into v1: each v1 thread loads its 4 input rows from global
//      (L2-hot halo) and computes the horizontal filter in registers -- the
//      6240-float h1 LDS buffer and one barrier are gone.
//  (b) back half runs as two 2-plane passes (lo planes, then hi planes) so the
//      per-wave scratch halves to 432 floats. No duplicated FMAs (lo/hi h2
//      parts are independent); only L1 float2 reads repeat.
__global__ void __launch_bounds__(512, 8) k_wpt_fused(
    const float* __restrict__ p, const float* __restrict__ t,
    float* __restrict__ partial) {
    constexpr int N0 = 512, N1 = 257, N2 = 130, N3 = 66;

    __shared__ __align__(16) float sA[6080];  // L1 bands 4 x 38 rows x stride 40
    __shared__ __align__(16) float sB[3456];  // 8 wave scratches [2][12][18]
    __shared__ float wsum[8];

    // XCD-chunked swizzle: 15552 = 8 * 1944 (bijective)
    int bid = blockIdx.x;
    int swz = (bid & 7) * (int)(gridDim.x >> 3) + (bid >> 3);
    int img = swz / 81;
    int tt = swz - img * 81;
    int TA = (tt / 9) * 8;
    int TB = (tt % 9) * 8;

    const int tid = threadIdx.x;
    const size_t ibase = (size_t)img * (N0 * N0);

    const int O0r = 8 * TA - 14, O0c = 8 * TB - 16;  // col origin 16B-aligned
    const int O1r = 4 * TA - 6, O1c = 4 * TB - 6;
    const int O2r = 2 * TA - 2, O2c = 2 * TB - 2;
    const bool edge = (TA == 0) || (TA == 64) || (TB == 0) || (TB == 64);

    // ---- fused h1+v1 from global: 380 threads, thread = (r1 0..37, k 0..9) ----
    // Thread produces L1 cols 4k..4k+3 of row r1 for all 4 bands. L1 col m taps
    // global cols A+2d+2..A+2d+5 where A = O0c+8k (16B-aligned), d = m-4k.
    if (tid < 380) {
        const int r1 = tid / 10, k = tid - (tid / 10) * 10;
        const int A = O0c + 8 * k;
        const bool vec = ((unsigned)A <= 504u);   // A>=0 && A+7<=511
        const int q2 = (A <= 500) ? 8 : 4;        // 3rd quad (cols feeding pads may dup)
        float b0[4] = {0.f, 0.f, 0.f, 0.f}, b1[4] = {0.f, 0.f, 0.f, 0.f};
        float b2[4] = {0.f, 0.f, 0.f, 0.f}, b3[4] = {0.f, 0.f, 0.f, 0.f};
#pragma unroll
        for (int u = 0; u < 4; ++u) {
            const int gr = reflect_idx(O0r + 2 * r1 + u, N0);
            const float* __restrict__ pr = p + ibase + (size_t)gr * N0;
            const float* __restrict__ tr = t + ibase + (size_t)gr * N0;
            float v[12];
            if (vec) {
                const float4 p0 = *(const float4*)(pr + A);
                const float4 p1 = *(const float4*)(pr + A + 4);
                const float4 p2 = *(const float4*)(pr + A + q2);
                const float4 t0 = *(const float4*)(tr + A);
                const float4 t1 = *(const float4*)(tr + A + 4);
                const float4 t2 = *(const float4*)(tr + A + q2);
                v[0] = p0.x - t0.x; v[1] = p0.y - t0.y; v[2] = p0.z - t0.z; v[3] = p0.w - t0.w;
                v[4] = p1.x - t1.x; v[5] = p1.y - t1.y; v[6] = p1.z - t1.z; v[7] = p1.w - t1.w;
                v[8] = p2.x - t2.x; v[9] = p2.y - t2.y; v[10] = p2.z - t2.z; v[11] = p2.w - t2.w;
            } else {
#pragma unroll
                for (int x = 0; x < 12; ++x) {
                    int gc = reflect_idx(A + x, N0);
                    v[x] = pr[gc] - tr[gc];
                }
            }
            float lo[4], hi[4];
#pragma unroll
            for (int d = 0; d < 4; ++d) {
                lo[d] = F_LO0 * v[2 * d + 2] + F_LO1 * v[2 * d + 3] +
                        F_LO2 * v[2 * d + 4] + F_LO3 * v[2 * d + 5];
                hi[d] = F_HI0 * v[2 * d + 2] + F_HI1 * v[2 * d + 3] +
                        F_HI2 * v[2 * d + 4] + F_HI3 * v[2 * d + 5];
            }
            const float cl = (u == 0) ? F_LO0 : (u == 1) ? F_LO1 : (u == 2) ? F_LO2 : F_LO3;
            const float ch = (u == 0) ? F_HI0 : (u == 1) ? F_HI1 : (u == 2) ? F_HI2 : F_HI3;
#pragma unroll
            for (int d = 0; d < 4; ++d) {
                b0[d] += cl * lo[d];
                b1[d] += ch * lo[d];
                b2[d] += cl * hi[d];
                b3[d] += ch * hi[d];
            }
        }
        const int wo = r1 * 40 + 4 * k;
        *(float4*)(sA + wo) = make_float4(b0[0], b0[1], b0[2], b0[3]);
        *(float4*)(sA + 1520 + wo) = make_float4(b1[0], b1[1], b1[2], b1[3]);
        *(float4*)(sA + 3040 + wo) = make_float4(b2[0], b2[1], b2[2], b2[3]);
        *(float4*)(sA + 4560 + wo) = make_float4(b3[0], b3[1], b3[2], b3[3]);
    }
    __syncthreads();
    if (edge) {  // patch reflected L1 slots (sources are fixed points: no race)
#pragma unroll
        for (int it = 0; it < 3; ++it) {
            int e = it * 512 + tid;
            if (e < 1444) {
                int lr = e / 38, lc = e - lr * 38;
                int sr = reflect_idx(O1r + lr, N1) - O1r;
                int sc = reflect_idx(O1c + lc, N1) - O1c;
                if ((sr != lr || sc != lc) && (unsigned)sr < 38u && (unsigned)sc < 38u) {
                    int da = lr * 40 + lc;
                    int sa = sr * 40 + sc;
                    sA[da] = sA[sa];
                    sA[1520 + da] = sA[1520 + sa];
                    sA[3040 + da] = sA[3040 + sa];
                    sA[4560 + da] = sA[4560 + sa];
                }
            }
        }
        __syncthreads();
    }

    // ============ wave-autonomous levels 2+3, two 2-plane passes ============
    const int w = tid >> 6;
    const int ln = tid & 63;
    const int bnd = w >> 1;       // level-1 band 0..3
    const int hf = w & 1;         // row half
    const int off = hf * 6;       // L2 tile rows off..off+11
    float* scr = sB + w * 432;    // private [2][12][18]
    const float* L1b = sA + bnd * 1520;

    float local = 0.f;
#pragma unroll
    for (int pass = 0; pass < 2; ++pass) {
        // L2 pair: lanes (c 0..17, s 0..2), 4 trips of 3 rows
        if (ln < 54) {
            const int c = ln % 18, s = ln / 18;
#pragma unroll
            for (int tq = 0; tq < 4; ++tq) {
                const int r2l = 3 * tq + s;  // 0..11
                const float* base = L1b + (2 * (off + r2l)) * 40 + 2 * c;
                float f[4];
#pragma unroll
                for (int u = 0; u < 4; ++u) {
                    float2 a = *(const float2*)(base + u * 40);
                    float2 d = *(const float2*)(base + u * 40 + 2);
                    f[u] = (pass == 0)
                        ? F_LO0 * a.x + F_LO1 * a.y + F_LO2 * d.x + F_LO3 * d.y
                        : F_HI0 * a.x + F_HI1 * a.y + F_HI2 * d.x + F_HI3 * d.y;
                }
                int sl = r2l * 18 + c;
                scr[sl]       = F_LO0 * f[0] + F_LO1 * f[1] + F_LO2 * f[2] + F_LO3 * f[3];
                scr[sl + 216] = F_HI0 * f[0] + F_HI1 * f[1] + F_HI2 * f[2] + F_HI3 * f[3];
            }
        }
        // wave-local reflect patch of this pass's 2 planes (edge blocks only)
        if (edge) {
#pragma unroll
            for (int q = 0; q < 4; ++q) {
                int e = q * 54 + ln;
                if (ln < 54 && e < 216) {
                    int lr = e / 18, lc = e - lr * 18;
                    int srt = reflect_idx(O2r + off + lr, N2) - O2r - off;
                    int sct = reflect_idx(O2c + lc, N2) - O2c;
                    if ((srt != lr || sct != lc) &&
                        (unsigned)srt < 12u && (unsigned)sct < 18u) {
                        int d = lr * 18 + lc, sidx = srt * 18 + sct;
                        scr[d] = scr[sidx];
                        scr[d + 216] = scr[sidx + 216];
                    }
                }
            }
        }
        // h3+v3 on the 2 planes: lanes (pp, r3, j) = 2 x 4 x 8, one item each
        {
            const int pp = ln >> 5, rem = ln & 31, r3 = rem >> 3, j = rem & 7;
            const int i = hf * 4 + r3;       // L3 tile row 0..7
            const int sr0 = 2 * r3 + hf * 2; // scratch row base
            const bool valid = (TA + i < N3) && (TB + j < N3);
            const float* pb = scr + pp * 216 + sr0 * 18 + 2 * j;
            float lo[4], hi[4];
#pragma unroll
            for (int u = 0; u < 4; ++u) {
                float2 a = *(const float2*)(pb + u * 18);
                float2 d = *(const float2*)(pb + u * 18 + 2);
                lo[u] = F_LO0 * a.x + F_LO1 * a.y + F_LO2 * d.x + F_LO3 * d.y;
                hi[u] = F_HI0 * a.x + F_HI1 * a.y + F_HI2 * d.x + F_HI3 * d.y;
            }
            float o0 = F_LO0 * lo[0] + F_LO1 * lo[1] + F_LO2 * lo[2] + F_LO3 * lo[3];
            float o1 = F_HI0 * lo[0] + F_HI1 * lo[1] + F_HI2 * lo[2] + F_HI3 * lo[3];
            float o2 = F_LO0 * hi[0] + F_LO1 * hi[1] + F_LO2 * hi[2] + F_LO3 * hi[3];
            float o3 = F_HI0 * hi[0] + F_HI1 * hi[1] + F_HI2 * hi[2] + F_HI3 * hi[3];
            if (valid) {
                float w00 = (bnd == 0 && pass == 0 && pp == 0) ? 0.5f : 1.0f;
                local += w00 * o0 * o0 + o1 * o1 + o2 * o2 + o3 * o3;
            }
        }
    }

    // block reduction: 8 waves, one plain store per block (no atomic)
#pragma unroll
    for (int o = 32; o > 0; o >>= 1) local += __shfl_down(local, o, 64);
    if (ln == 0) wsum[w] = local;
    __syncthreads();
    if (tid == 0) {
        float ssum = 0.f;
#pragma unroll
        for (int x = 0; x < 8; ++x) ssum += wsum[x];
        partial[blockIdx.x] = ssum;
    }
}

// Final reduction: sum 15552 per-block partials -> out[0]. Single block.
__global__ void __launch_bounds__(1024) k_reduce(const float* __restrict__ part,
                                                 float* __restrict__ out,
                                                 int n4, float inv_den) {
    const int tid = threadIdx.x;
    float s = 0.f;
    const float4* p4 = (const float4*)part;
    for (int i = tid; i < n4; i += 1024) {
        float4 v = p4[i];
        s += v.x + v.y + v.z + v.w;
    }
#pragma unroll
    for (int o = 32; o > 0; o >>= 1) s += __shfl_down(s, o, 64);
    __shared__ float ws_[16];
    int w = tid >> 6;
    if ((tid & 63) == 0) ws_[w] = s;
    __syncthreads();
    if (tid == 0) {
        float tot = 0.f;
#pragma unroll
        for (int i = 0; i < 16; ++i) tot += ws_[i];
        out[0] = tot * inv_den;
    }
}

extern "C" void kernel_launch(void* const* d_in, const int* in_sizes, int n_in,
                              void* d_out, int out_size, void* d_ws, size_t ws_size,
                              hipStream_t stream) {
    const float* preds = (const float*)d_in[0];
    const float* targets = (const float*)d_in[1];
    float* out = (float*)d_out;
    float* partial = (float*)d_ws;  // 15552 floats = 62 KB

    const float inv_den = 1.0f / (192.0f * 66.0f * 66.0f);
    const int nblk = 192 * 9 * 9;  // 15552, divisible by 8

    k_wpt_fused<<<dim3(nblk), dim3(512), 0, stream>>>(preds, targets, partial);
    k_reduce<<<dim3(1), dim3(1024), 0, stream>>>(partial, out, nblk / 4, inv_den);
}

// Round 12
// 222.561 us; speedup vs baseline: 2.5195x; 2.5195x over previous
//
#include <hip/hip_runtime.h>

// db2 filters, pre-flipped (cross-correlation form used by ptwt)
#define F_LO0 0.4829629131445341f
#define F_LO1 0.8365163037378079f
#define F_LO2 0.22414386804185735f
#define F_LO3 (-0.12940952255092145f)
#define F_HI0 (-0.12940952255092145f)
#define F_HI1 (-0.22414386804185735f)
#define F_HI2 0.8365163037378079f
#define F_HI3 (-0.4829629131445341f)

__device__ __forceinline__ int reflect_idx(int r, int n) {
    r = (r < 0) ? -r : r;
    r = (r >= n) ? 2 * n - 2 - r : r;
    return r;
}

// vertical 4-tap filter on float4 lanes (4 columns at once)
__device__ __forceinline__ float4 vfilt(const float4 a, const float4 b,
                                        const float4 c, const float4 d,
                                        float c0, float c1, float c2, float c3) {
    return make_float4(c0 * a.x + c1 * b.x + c2 * c.x + c3 * d.x,
                       c0 * a.y + c1 * b.y + c2 * c.y + c3 * d.y,
                       c0 * a.z + c1 * b.z + c2 * c.z + c3 * d.z,
                       c0 * a.w + c1 * b.w + c2 * c.w + c3 * d.w);
}

// Fused 3-level WPT + weighted squared-sum.
// R12: clean 4-blocks/CU experiment. Front end = R10 (h1 reads global once per
// row, 40 VGPR, FETCH 197 MB). LDS cut 52->38.4 KB via (a) 44-row h1 ring
// buffer (h1/v1 split into 2 chunks, +2 barriers) and (b) two-pass back half
// (scratch 8x432, verified in R11). Every 3-blocks/CU config has been pinned
// at 230-250 us dispatch regardless of internals; this tests 4 blocks/CU.
__global__ void __launch_bounds__(512, 8) k_wpt_fused(
    const float* __restrict__ p, const float* __restrict__ t,
    float* __restrict__ partial) {
    constexpr int N0 = 512, N1 = 257, N2 = 130, N3 = 66;

    __shared__ __align__(16) float sA[6080];  // L1 bands 4 x 38 rows x stride 40
    __shared__ __align__(16) float sB[3520];  // h1 ring 44 rows x 40, lo(0)/hi(1760); reused as 8x432 scratch
    __shared__ float wsum[8];

    // XCD-chunked swizzle: 15552 = 8 * 1944 (bijective)
    int bid = blockIdx.x;
    int swz = (bid & 7) * (int)(gridDim.x >> 3) + (bid >> 3);
    int img = swz / 81;
    int tt = swz - img * 81;
    int TA = (tt / 9) * 8;
    int TB = (tt % 9) * 8;

    const int tid = threadIdx.x;
    const size_t ibase = (size_t)img * (N0 * N0);

    const int O0r = 8 * TA - 14, O0c = 8 * TB - 16;  // col origin 16B-aligned
    const int O1r = 4 * TA - 6, O1c = 4 * TB - 6;
    const int O2r = 2 * TA - 2, O2c = 2 * TB - 2;
    const bool edge = (TA == 0) || (TA == 64) || (TB == 0) || (TB == 64);

    // ---------- h1 row macro-body: global row -> h1 lo/hi at ring slot ----------
    // thread handles (row r, group k 0..4): 8 output cols 8k..8k+7 from global
    // cols gc0..gc0+19, gc0 = O0c+16k (16B-aligned).
#define H1_ROW(r, k, slot)                                                          \
    {                                                                               \
        const int grr = reflect_idx(O0r + (r), N0);                                 \
        const float* __restrict__ prow = p + ibase + (size_t)grr * N0;              \
        const float* __restrict__ trow = t + ibase + (size_t)grr * N0;              \
        const int gc0 = O0c + 16 * (k);                                             \
        float v[20];                                                                \
        if ((unsigned)gc0 <= 492u) {                                                \
            _Pragma("unroll") for (int q = 0; q < 5; ++q) {                         \
                const float4 pv = *(const float4*)(prow + gc0 + 4 * q);             \
                const float4 tv = *(const float4*)(trow + gc0 + 4 * q);             \
                v[4 * q + 0] = pv.x - tv.x;                                         \
                v[4 * q + 1] = pv.y - tv.y;                                         \
                v[4 * q + 2] = pv.z - tv.z;                                         \
                v[4 * q + 3] = pv.w - tv.w;                                         \
            }                                                                       \
        } else {                                                                    \
            _Pragma("unroll") for (int x = 0; x < 20; ++x) {                        \
                int gc = reflect_idx(gc0 + x, N0);                                  \
                v[x] = prow[gc] - trow[gc];                                         \
            }                                                                       \
        }                                                                           \
        float* dst = sB + (slot) * 40 + 8 * (k);                                    \
        *(float4*)(dst) = make_float4(                                              \
            F_LO0 * v[2] + F_LO1 * v[3] + F_LO2 * v[4] + F_LO3 * v[5],              \
            F_LO0 * v[4] + F_LO1 * v[5] + F_LO2 * v[6] + F_LO3 * v[7],              \
            F_LO0 * v[6] + F_LO1 * v[7] + F_LO2 * v[8] + F_LO3 * v[9],              \
            F_LO0 * v[8] + F_LO1 * v[9] + F_LO2 * v[10] + F_LO3 * v[11]);           \
        *(float4*)(dst + 4) = make_float4(                                          \
            F_LO0 * v[10] + F_LO1 * v[11] + F_LO2 * v[12] + F_LO3 * v[13],          \
            F_LO0 * v[12] + F_LO1 * v[13] + F_LO2 * v[14] + F_LO3 * v[15],          \
            F_LO0 * v[14] + F_LO1 * v[15] + F_LO2 * v[16] + F_LO3 * v[17],          \
            F_LO0 * v[16] + F_LO1 * v[17] + F_LO2 * v[18] + F_LO3 * v[19]);         \
        *(float4*)(dst + 1760) = make_float4(                                       \
            F_HI0 * v[2] + F_HI1 * v[3] + F_HI2 * v[4] + F_HI3 * v[5],              \
            F_HI0 * v[4] + F_HI1 * v[5] + F_HI2 * v[6] + F_HI3 * v[7],              \
            F_HI0 * v[6] + F_HI1 * v[7] + F_HI2 * v[8] + F_HI3 * v[9],              \
            F_HI0 * v[8] + F_HI1 * v[9] + F_HI2 * v[10] + F_HI3 * v[11]);           \
        *(float4*)(dst + 1764) = make_float4(                                       \
            F_HI0 * v[10] + F_HI1 * v[11] + F_HI2 * v[12] + F_HI3 * v[13],          \
            F_HI0 * v[12] + F_HI1 * v[13] + F_HI2 * v[14] + F_HI3 * v[15],          \
            F_HI0 * v[14] + F_HI1 * v[15] + F_HI2 * v[16] + F_HI3 * v[17],          \
            F_HI0 * v[16] + F_HI1 * v[17] + F_HI2 * v[18] + F_HI3 * v[19]);         \
    }

    // v1 row macro-body: 4 h1 ring rows -> L1 row r1, cols 4k..4k+3, 4 bands
#define V1_ROW(r1, k)                                                               \
    {                                                                               \
        const int hr = 2 * (r1);                                                    \
        const int s0 = (hr >= 44) ? hr - 44 : hr;                                   \
        const int s1 = (hr + 1 >= 44) ? hr - 43 : hr + 1;                           \
        const int s2 = (hr + 2 >= 44) ? hr - 42 : hr + 2;                           \
        const int s3 = (hr + 3 >= 44) ? hr - 41 : hr + 3;                           \
        const int co = 4 * (k);                                                     \
        float4 L0 = *(const float4*)(sB + s0 * 40 + co);                            \
        float4 L1v = *(const float4*)(sB + s1 * 40 + co);                           \
        float4 L2v = *(const float4*)(sB + s2 * 40 + co);                           \
        float4 L3v = *(const float4*)(sB + s3 * 40 + co);                           \
        float4 H0 = *(const float4*)(sB + s0 * 40 + 1760 + co);                     \
        float4 H1 = *(const float4*)(sB + s1 * 40 + 1760 + co);                     \
        float4 H2 = *(const float4*)(sB + s2 * 40 + 1760 + co);                     \
        float4 H3 = *(const float4*)(sB + s3 * 40 + 1760 + co);                     \
        float4 b0 = vfilt(L0, L1v, L2v, L3v, F_LO0, F_LO1, F_LO2, F_LO3);           \
        float4 b1 = vfilt(L0, L1v, L2v, L3v, F_HI0, F_HI1, F_HI2, F_HI3);           \
        float4 b2 = vfilt(H0, H1, H2, H3, F_LO0, F_LO1, F_LO2, F_LO3);              \
        float4 b3 = vfilt(H0, H1, H2, H3, F_HI0, F_HI1, F_HI2, F_HI3);              \
        const int wo = (r1) * 40 + co;                                              \
        *(float4*)(sA + wo) = b0;                                                   \
        *(float4*)(sA + 1520 + wo) = b1;                                            \
        *(float4*)(sA + 3040 + wo) = b2;                                            \
        *(float4*)(sA + 4560 + wo) = b3;                                            \
    }

    // Phase A: h1 rows 0..43 (slots 0..43), 220 threads
    if (tid < 220) {
        const int r = tid / 5, k = tid - (tid / 5) * 5;
        H1_ROW(r, k, r);
    }
    __syncthreads();
    // Phase B: v1 rows 0..20 (needs h1 rows <= 43), 210 threads
    if (tid < 210) {
        const int r1 = tid / 10, k = tid - (tid / 10) * 10;
        V1_ROW(r1, k);
    }
    __syncthreads();
    // Phase C: h1 rows 44..77 -> slots 0..33, 170 threads
    if (tid < 170) {
        const int r = 44 + tid / 5, k = tid - (tid / 5) * 5;
        H1_ROW(r, k, r - 44);
    }
    __syncthreads();
    // Phase D: v1 rows 21..37 (h1 rows 42..77: slots 42,43,0..33), 170 threads
    if (tid < 170) {
        const int r1 = 21 + tid / 10, k = tid - (tid / 10) * 10;
        V1_ROW(r1, k);
    }
    __syncthreads();
    if (edge) {  // patch reflected L1 slots (sources are fixed points: no race)
#pragma unroll
        for (int it = 0; it < 3; ++it) {
            int e = it * 512 + tid;
            if (e < 1444) {
                int lr = e / 38, lc = e - lr * 38;
                int sr = reflect_idx(O1r + lr, N1) - O1r;
                int sc = reflect_idx(O1c + lc, N1) - O1c;
                if ((sr != lr || sc != lc) && (unsigned)sr < 38u && (unsigned)sc < 38u) {
                    int da = lr * 40 + lc;
                    int sa = sr * 40 + sc;
                    sA[da] = sA[sa];
                    sA[1520 + da] = sA[1520 + sa];
                    sA[3040 + da] = sA[3040 + sa];
                    sA[4560 + da] = sA[4560 + sa];
                }
            }
        }
        __syncthreads();
    }

    // ============ wave-autonomous levels 2+3, two 2-plane passes ============
    // (sB's h1 data is dead after phase D; reuse as per-wave scratch)
    const int w = tid >> 6;
    const int ln = tid & 63;
    const int bnd = w >> 1;       // level-1 band 0..3
    const int hf = w & 1;         // row half
    const int off = hf * 6;       // L2 tile rows off..off+11
    float* scr = sB + w * 432;    // private [2][12][18]
    const float* L1b = sA + bnd * 1520;

    float local = 0.f;
#pragma unroll
    for (int pass = 0; pass < 2; ++pass) {
        // L2 pair: lanes (c 0..17, s 0..2), 4 trips of 3 rows
        if (ln < 54) {
            const int c = ln % 18, s = ln / 18;
#pragma unroll
            for (int tq = 0; tq < 4; ++tq) {
                const int r2l = 3 * tq + s;  // 0..11
                const float* base = L1b + (2 * (off + r2l)) * 40 + 2 * c;
                float f[4];
#pragma unroll
                for (int u = 0; u < 4; ++u) {
                    float2 a = *(const float2*)(base + u * 40);
                    float2 d = *(const float2*)(base + u * 40 + 2);
                    f[u] = (pass == 0)
                        ? F_LO0 * a.x + F_LO1 * a.y + F_LO2 * d.x + F_LO3 * d.y
                        : F_HI0 * a.x + F_HI1 * a.y + F_HI2 * d.x + F_HI3 * d.y;
                }
                int sl = r2l * 18 + c;
                scr[sl]       = F_LO0 * f[0] + F_LO1 * f[1] + F_LO2 * f[2] + F_LO3 * f[3];
                scr[sl + 216] = F_HI0 * f[0] + F_HI1 * f[1] + F_HI2 * f[2] + F_HI3 * f[3];
            }
        }
        // wave-local reflect patch of this pass's 2 planes (edge blocks only)
        if (edge) {
#pragma unroll
            for (int q = 0; q < 4; ++q) {
                int e = q * 54 + ln;
                if (ln < 54 && e < 216) {
                    int lr = e / 18, lc = e - lr * 18;
                    int srt = reflect_idx(O2r + off + lr, N2) - O2r - off;
                    int sct = reflect_idx(O2c + lc, N2) - O2c;
                    if ((srt != lr || sct != lc) &&
                        (unsigned)srt < 12u && (unsigned)sct < 18u) {
                        int d = lr * 18 + lc, sidx = srt * 18 + sct;
                        scr[d] = scr[sidx];
                        scr[d + 216] = scr[sidx + 216];
                    }
                }
            }
        }
        // h3+v3 on the 2 planes: lanes (pp, r3, j) = 2 x 4 x 8, one item each
        {
            const int pp = ln >> 5, rem = ln & 31, r3 = rem >> 3, j = rem & 7;
            const int i = hf * 4 + r3;       // L3 tile row 0..7
            const int sr0 = 2 * r3 + hf * 2; // scratch row base
            const bool valid = (TA + i < N3) && (TB + j < N3);
            const float* pb = scr + pp * 216 + sr0 * 18 + 2 * j;
            float lo[4], hi[4];
#pragma unroll
            for (int u = 0; u < 4; ++u) {
                float2 a = *(const float2*)(pb + u * 18);
                float2 d = *(const float2*)(pb + u * 18 + 2);
                lo[u] = F_LO0 * a.x + F_LO1 * a.y + F_LO2 * d.x + F_LO3 * d.y;
                hi[u] = F_HI0 * a.x + F_HI1 * a.y + F_HI2 * d.x + F_HI3 * d.y;
            }
            float o0 = F_LO0 * lo[0] + F_LO1 * lo[1] + F_LO2 * lo[2] + F_LO3 * lo[3];
            float o1 = F_HI0 * lo[0] + F_HI1 * lo[1] + F_HI2 * lo[2] + F_HI3 * lo[3];
            float o2 = F_LO0 * hi[0] + F_LO1 * hi[1] + F_LO2 * hi[2] + F_LO3 * hi[3];
            float o3 = F_HI0 * hi[0] + F_HI1 * hi[1] + F_HI2 * hi[2] + F_HI3 * hi[3];
            if (valid) {
                float w00 = (bnd == 0 && pass == 0 && pp == 0) ? 0.5f : 1.0f;
                local += w00 * o0 * o0 + o1 * o1 + o2 * o2 + o3 * o3;
            }
        }
    }

    // block reduction: 8 waves, one plain store per block (no atomic)
#pragma unroll
    for (int o = 32; o > 0; o >>= 1) local += __shfl_down(local, o, 64);
    if (ln == 0) wsum[w] = local;
    __syncthreads();
    if (tid == 0) {
        float ssum = 0.f;
#pragma unroll
        for (int x = 0; x < 8; ++x) ssum += wsum[x];
        partial[blockIdx.x] = ssum;
    }
}

// Final reduction: sum 15552 per-block partials -> out[0]. Single block.
__global__ void __launch_bounds__(1024) k_reduce(const float* __restrict__ part,
                                                 float* __restrict__ out,
                                                 int n4, float inv_den) {
    const int tid = threadIdx.x;
    float s = 0.f;
    const float4* p4 = (const float4*)part;
    for (int i = tid; i < n4; i += 1024) {
        float4 v = p4[i];
        s += v.x + v.y + v.z + v.w;
    }
#pragma unroll
    for (int o = 32; o > 0; o >>= 1) s += __shfl_down(s, o, 64);
    __shared__ float ws_[16];
    int w = tid >> 6;
    if ((tid & 63) == 0) ws_[w] = s;
    __syncthreads();
    if (tid == 0) {
        float tot = 0.f;
#pragma unroll
        for (int i = 0; i < 16; ++i) tot += ws_[i];
        out[0] = tot * inv_den;
    }
}

extern "C" void kernel_launch(void* const* d_in, const int* in_sizes, int n_in,
                              void* d_out, int out_size, void* d_ws, size_t ws_size,
                              hipStream_t stream) {
    const float* preds = (const float*)d_in[0];
    const float* targets = (const float*)d_in[1];
    float* out = (float*)d_out;
    float* partial = (float*)d_ws;  // 15552 floats = 62 KB

    const float inv_den = 1.0f / (192.0f * 66.0f * 66.0f);
    const int nblk = 192 * 9 * 9;  // 15552, divisible by 8

    k_wpt_fused<<<dim3(nblk), dim3(512), 0, stream>>>(preds, targets, partial);
    k_reduce<<<dim3(1), dim3(1024), 0, stream>>>(partial, out, nblk / 4, inv_den);
}